// Round 1
// 419.769 us; speedup vs baseline: 1.1007x; 1.1007x over previous
//
#include <hip/hip_runtime.h>

// ---------------------------------------------------------------------------
// RGCN (basis decomposition), 2 layers. N=50000, E=1e6, H=128, O=64, R=16.
// Round 10: round 9 was still exposed-latency-bound (MfmaUtil 17%, VALU 21%,
// HBM 10%, ~2286 cy/chunk vs ~130 cy MFMA). The per-phase serial chain
// ebuf-load (~900cy) -> dependent gather (~600-900cy) -> ds_write/barrier
// was hidden only by ~400cy of compute. Changes:
//  - Depth-3 register pipeline held ACROSS barriers: phase k issues
//    ebuf(k+3); issues gathers(k+2) from ebuf regs landed one phase ago;
//    writes chunk k+1 into xs[cb^1]/pmat[cb^1] from gather regs issued at
//    k-1. Every load gets >= 1 full phase of latency cover; the pre-barrier
//    wait becomes a counted vmcnt (prefetches stay in flight), not a drain.
//  - Per-block chunk descriptor list (base,nRows,rel) built once in LDS:
//    removes per-phase offsets/counts global loads + branchy bin walk.
// VGPR cost ~+35 (was 64; 3 waves/SIMD allows ~168). LDS +~1.8KB (desc),
// still 3 blocks/CU. MFMA layouts identical to rounds 3-9 (passing).
// ---------------------------------------------------------------------------

typedef short bf16x8 __attribute__((ext_vector_type(8)));
typedef float f32x4 __attribute__((ext_vector_type(4)));

#define RELS 16
#define HDIM 128
#define DSTBLK 66
#define MT_P 5    // ceil(66/16): pmat has 80 rows
#define CHUNK 32
#define MAXBINS 12288
#define MAXCH 96  // chunks/block: mean ~49; needs edges>2592 (35 sigma) to overflow

__device__ inline unsigned short f2bf(float f) {
  unsigned int u = __float_as_uint(f);
  unsigned int r = u + 0x7FFFu + ((u >> 16) & 1u);
  return (unsigned short)(r >> 16);
}

__global__ void cvt_bf16(const float* __restrict__ in, unsigned short* __restrict__ out, int n8) {
  int i = blockIdx.x * blockDim.x + threadIdx.x;
  if (i >= n8) return;
  float4 a = ((const float4*)in)[i * 2];
  float4 b = ((const float4*)in)[i * 2 + 1];
  uint4 o;
  o.x = (unsigned)f2bf(a.x) | ((unsigned)f2bf(a.y) << 16);
  o.y = (unsigned)f2bf(a.z) | ((unsigned)f2bf(a.w) << 16);
  o.z = (unsigned)f2bf(b.x) | ((unsigned)f2bf(b.y) << 16);
  o.w = (unsigned)f2bf(b.z) | ((unsigned)f2bf(b.w) << 16);
  ((uint4*)out)[i] = o;
}

// Wt[r][o][k] (bf16, transposed) = sum_b comp[r,b] * V[b,k,o]
__global__ void compute_w(const float* __restrict__ comp, const float* __restrict__ V,
                          unsigned short* __restrict__ Wt, int IO) {
  int idx = blockIdx.x * blockDim.x + threadIdx.x;
  if (idx >= RELS * IO * HDIM) return;
  int k = idx & (HDIM - 1);
  int o = (idx >> 7) % IO;
  int r = idx / (IO * HDIM);
  float s = 0.f;
#pragma unroll
  for (int b = 0; b < RELS; b++)
    s = fmaf(comp[r * RELS + b], V[(size_t)b * HDIM * IO + (size_t)k * IO + o], s);
  Wt[idx] = f2bf(s);
}

__global__ void hist_bins(const int* __restrict__ dst, const int* __restrict__ etype,
                          int n, int nbins, int* __restrict__ counts) {
  __shared__ int lh[MAXBINS];
  for (int j = threadIdx.x; j < nbins; j += blockDim.x) lh[j] = 0;
  __syncthreads();
  for (int i = blockIdx.x * blockDim.x + threadIdx.x; i < n; i += gridDim.x * blockDim.x)
    atomicAdd(&lh[(dst[i] / DSTBLK) * RELS + etype[i]], 1);
  __syncthreads();
  for (int j = threadIdx.x; j < nbins; j += blockDim.x) {
    int c = lh[j];
    if (c) atomicAdd(&counts[j], c);
  }
}

// exclusive scan of counts padded to multiples of 16 (parallel prefix)
__global__ void scan_offsets(const int* __restrict__ counts, int* __restrict__ offsets, int nbins) {
  __shared__ int csum[256];
  const int t = threadIdx.x;
  const int CH = (nbins + 255) / 256;
  int lo = t * CH, hi = min(lo + CH, nbins);
  int s = 0;
  for (int i = lo; i < hi; i++) s += (counts[i] + 15) & ~15;
  csum[t] = s;
  __syncthreads();
#pragma unroll
  for (int d = 1; d < 256; d <<= 1) {  // Hillis-Steele inclusive scan
    int v = (t >= d) ? csum[t - d] : 0;
    __syncthreads();
    csum[t] += v;
    __syncthreads();
  }
  int run = (t == 0) ? 0 : csum[t - 1];
  for (int i = lo; i < hi; i++) {
    offsets[i] = run;
    run += (counts[i] + 15) & ~15;
  }
  if (lo < nbins && hi == nbins) offsets[nbins] = run;
}

// ebuf[p] = {src | dloc<<20, norm_f32_bits}; dloc = d % DSTBLK (7 bits).
// Pad slots unwritten; all consumers guard by real counts.
__global__ void scatter_bins(const int* __restrict__ src, const int* __restrict__ dst,
                             const int* __restrict__ etype, const float* __restrict__ norm,
                             int n, const int* __restrict__ offsets, int* __restrict__ cursor,
                             uint2* __restrict__ ebuf) {
  for (int i = blockIdx.x * blockDim.x + threadIdx.x; i < n; i += gridDim.x * blockDim.x) {
    int d = dst[i];
    int blk = d / DSTBLK;
    int b = blk * RELS + etype[i];
    int p = offsets[b] + atomicAdd(&cursor[b], 1);
    ebuf[p] = make_uint2((unsigned)src[i] | ((unsigned)(d - blk * DSTBLK) << 20),
                         __float_as_uint(norm[i]));
  }
}

// One block owns DSTBLK nodes; walks a precomputed chunk-descriptor list.
// Depth-3 pipeline: at phase ci we (1) issue ebuf loads for ci+3, (2) GEMM1
// on xs[cb], (3) issue gathers for ci+2 from ebuf regs loaded at ci-1,
// (4) agg on pmat[cb], (5) write chunk ci+1 from gather regs issued at ci-1,
// (6) rotate registers, barrier. All loads get >=1 full phase of cover.
// Wave w owns out columns [w*OUT/4, +OUT/4).
template <int OUT, bool BF16_RELU_OUT>
__launch_bounds__(256, 3)
__global__ void rgcn_layer(const unsigned short* __restrict__ Xb,  // [N][128] bf16
                           const unsigned short* __restrict__ Wt,  // [R][OUT][128] bf16
                           const uint2* __restrict__ ebuf,
                           const int* __restrict__ offsets, const int* __restrict__ counts,
                           const float* __restrict__ bias, void* __restrict__ Hout,
                           int nNodes) {
  constexpr int NT = OUT / 64;  // 2 (OUT=128) or 1 (OUT=64)
  __shared__ __align__(16) unsigned short xs[2][CHUNK][136];  // gathered src rows
  __shared__ __align__(16) unsigned short ys[OUT][40];        // messages^T, wave-local cols
  __shared__ __align__(16) unsigned short pmat[2][80][40];    // P[dloc][edge] = bf16(norm)
  __shared__ __align__(16) int4 descS[MAXCH];                 // {base, nRows, rel, 0}
  __shared__ int sBase[16], sCnt[16], sStart[17];

  const int t = threadIdx.x;
  const int w = t >> 6;
  const int lane = t & 63;
  const int quad = lane >> 4;
  const int l16 = lane & 15;
  const int r0 = t >> 4;     // gather row (this thread covers rows r0, r0+16)
  const int k8 = t & 15;     // gather 8-elem column piece
  const bool isHandler = (t & 7) == 0;
  const int myCol = t >> 3;  // handler-owned edge column (0..31, fixed)
  const int nodeBase = blockIdx.x * DSTBLK;
  const int binBase = blockIdx.x * RELS;
  const int colBase = w * (OUT / 4);

  // one-time zero (stale LDS may hold NaN bit patterns; 0 * NaN = NaN)
  for (int i = t; i < 2 * CHUNK * 136 / 8; i += 256) ((uint4*)xs)[i] = make_uint4(0, 0, 0, 0);
  for (int i = t; i < OUT * 40 / 8; i += 256) ((uint4*)ys)[i] = make_uint4(0, 0, 0, 0);
  for (int i = t; i < 2 * 80 * 40 / 8; i += 256) ((uint4*)pmat)[i] = make_uint4(0, 0, 0, 0);

  // build chunk descriptor list (bins in relation order -> few W reloads)
  if (t < 16) {
    sBase[t] = offsets[binBase + t];
    sCnt[t] = counts[binBase + t];
  }
  __syncthreads();  // covers zero-init + sBase/sCnt
  if (t == 0) {
    int run = 0;
#pragma unroll
    for (int b = 0; b < 16; b++) {
      sStart[b] = run;
      run += (sCnt[b] + CHUNK - 1) / CHUNK;
    }
    sStart[16] = min(run, MAXCH);
  }
  __syncthreads();
  if (t < 16) {
    int st = sStart[t], ba = sBase[t], c = sCnt[t];
    for (int j = 0; j * CHUNK < c; j++)
      if (st + j < MAXCH)
        descS[st + j] = make_int4(ba + j * CHUNK, min(CHUNK, c - j * CHUNK), t, 0);
  }
  __syncthreads();
  const int nCh = sStart[16];

  f32x4 pacc[MT_P][NT] = {};  // persistent dst accumulator

  // pipeline registers (live across barriers; VGPR headroom exists)
  uint2 EnE0, EnE1, EnEm;     // ebuf entries for chunk ci+1 (landed)
  uint2 En2E0, En2E1, En2Em;  // ebuf entries for chunk ci+2 (in flight ~1 phase)
  uint4 GnG0, GnG1;           // gathered rows for chunk ci+1 (in flight ~1 phase)
  int n1 = 0, n2 = 0;         // nRows of chunks ci+1, ci+2
  int pdA = -1, pdB = -1;     // handler prev-entry trackers (pdA = buffer written next)

  // prologue: stage chunk 0 into xs[0]/pmat[0]; prime the pipeline regs
  if (nCh > 0) {
    int4 d0 = descS[0];
    int4 d1 = (nCh > 1) ? descS[1] : make_int4(0, 0, 0, 0);
    int4 d2 = (nCh > 2) ? descS[2] : make_int4(0, 0, 0, 0);
    n1 = d1.y;
    n2 = d2.y;
    uint2 a0, a1, am;
    if (r0 < d0.y) a0 = ebuf[d0.x + r0];
    if (16 + r0 < d0.y) a1 = ebuf[d0.x + 16 + r0];
    if (isHandler && myCol < d0.y) am = ebuf[d0.x + myCol];
    if (r0 < n1) EnE0 = ebuf[d1.x + r0];
    if (16 + r0 < n1) EnE1 = ebuf[d1.x + 16 + r0];
    if (isHandler && myCol < n1) EnEm = ebuf[d1.x + myCol];
    if (r0 < n2) En2E0 = ebuf[d2.x + r0];
    if (16 + r0 < n2) En2E1 = ebuf[d2.x + 16 + r0];
    if (isHandler && myCol < n2) En2Em = ebuf[d2.x + myCol];
    // gather + write chunk 0 (full latency exposed once per block)
    if (r0 < d0.y)
      *(uint4*)&xs[0][r0][k8 * 8] =
          *(const uint4*)(Xb + (size_t)(a0.x & 0xFFFFFu) * HDIM + k8 * 8);
    if (16 + r0 < d0.y)
      *(uint4*)&xs[0][16 + r0][k8 * 8] =
          *(const uint4*)(Xb + (size_t)(a1.x & 0xFFFFFu) * HDIM + k8 * 8);
    if (isHandler && myCol < d0.y) {
      int dl = (int)(am.x >> 20) & 127;
      pmat[0][dl][myCol] = f2bf(__uint_as_float(am.y));
      pdB = dl;  // buffer-0 tracker; first loop phase writes buffer 1 via pdA
    }
    // issue gathers for chunk 1 (EnE* landed or nearly so by now)
    if (r0 < n1) GnG0 = *(const uint4*)(Xb + (size_t)(EnE0.x & 0xFFFFFu) * HDIM + k8 * 8);
    if (16 + r0 < n1) GnG1 = *(const uint4*)(Xb + (size_t)(EnE1.x & 0xFFFFFu) * HDIM + k8 * 8);
  }
  __syncthreads();

  int cb = 0;
  int curRel = -1;
  bf16x8 wf[4][NT];

  for (int ci = 0; ci < nCh; ci++) {
    int4 dc = descS[ci];
    const int nRows = dc.y;

    if (dc.z != curRel) {  // W fragments for this relation (register-resident)
      curRel = dc.z;
      const unsigned short* Wr = Wt + (size_t)curRel * OUT * HDIM;
#pragma unroll
      for (int ks = 0; ks < 4; ks++)
#pragma unroll
        for (int nt = 0; nt < NT; nt++)
          wf[ks][nt] = *(const bf16x8*)(Wr + (size_t)(colBase + nt * 16 + l16) * HDIM + ks * 32 + quad * 8);
    }

    // ---- (1) issue ebuf loads for chunk ci+3 (consumed at ci+1: ~1.3 phases) ----
    int4 d3 = make_int4(0, 0, 0, 0);
    if (ci + 3 < nCh) d3 = descS[ci + 3];
    uint2 EwE0, EwE1, EwEm;
    if (r0 < d3.y) EwE0 = ebuf[d3.x + r0];
    if (16 + r0 < d3.y) EwE1 = ebuf[d3.x + 16 + r0];
    if (isHandler && myCol < d3.y) EwEm = ebuf[d3.x + myCol];

    // ---- (2) GEMM1: Y = xs[cb] @ W_r, staged to wave-local ys^T columns ----
#pragma unroll
    for (int mt = 0; mt < 2; mt++) {
      if (mt * 16 < nRows) {  // wave-uniform
        f32x4 dacc[NT] = {};
#pragma unroll
        for (int ks = 0; ks < 4; ks++) {
          bf16x8 a = *(const bf16x8*)&xs[cb][mt * 16 + l16][ks * 32 + quad * 8];
#pragma unroll
          for (int nt = 0; nt < NT; nt++)
            dacc[nt] = __builtin_amdgcn_mfma_f32_16x16x32_bf16(a, wf[ks][nt], dacc[nt], 0, 0, 0);
        }
#pragma unroll
        for (int nt = 0; nt < NT; nt++) {
          uint2 pk;
          pk.x = (unsigned)f2bf(dacc[nt][0]) | ((unsigned)f2bf(dacc[nt][1]) << 16);
          pk.y = (unsigned)f2bf(dacc[nt][2]) | ((unsigned)f2bf(dacc[nt][3]) << 16);
          *(uint2*)&ys[colBase + nt * 16 + l16][mt * 16 + quad * 4] = pk;
        }
      }
    }

    // ---- (3) issue gathers for chunk ci+2 (ebuf regs landed ~1.3 phases ago;
    //          results consumed at ci+1 step 5: ~1.2 phases of cover) ----
    uint4 GwG0, GwG1;
    if (r0 < n2) GwG0 = *(const uint4*)(Xb + (size_t)(En2E0.x & 0xFFFFFu) * HDIM + k8 * 8);
    if (16 + r0 < n2) GwG1 = *(const uint4*)(Xb + (size_t)(En2E1.x & 0xFFFFFu) * HDIM + k8 * 8);

    // ---- (4) aggregation GEMM: pacc += P(norm) @ Y (single k=32 pass) ----
    // pmat[cb] barrier-protected; ys wave-local (same-wave LDS RAW in-order);
    // stale ys edge-columns have pmat == 0.
    {
      bf16x8 bfv[NT];
#pragma unroll
      for (int nt = 0; nt < NT; nt++)
        bfv[nt] = *(const bf16x8*)&ys[colBase + nt * 16 + l16][quad * 8];
#pragma unroll
      for (int mt = 0; mt < MT_P; mt++) {
        bf16x8 a = *(const bf16x8*)&pmat[cb][mt * 16 + l16][quad * 8];
#pragma unroll
        for (int nt = 0; nt < NT; nt++)
          pacc[mt][nt] = __builtin_amdgcn_mfma_f32_16x16x32_bf16(a, bfv[nt], pacc[mt][nt], 0, 0, 0);
      }
    }

    // ---- (5) write chunk ci+1 into the other buffers (gathers issued at ci-1:
    //          the pre-barrier wait is a counted vmcnt, newer loads in flight) ----
    if (r0 < n1) *(uint4*)&xs[cb ^ 1][r0][k8 * 8] = GnG0;
    if (16 + r0 < n1) *(uint4*)&xs[cb ^ 1][16 + r0][k8 * 8] = GnG1;
    if (isHandler) {
      if (pdA >= 0) pmat[cb ^ 1][pdA][myCol] = 0;  // clear own old entry
      if (myCol < n1) {
        int dl = (int)(EnEm.x >> 20) & 127;
        pmat[cb ^ 1][dl][myCol] = f2bf(__uint_as_float(EnEm.y));
        pdA = dl;
      } else {
        pdA = -1;
      }
    }
    { int tmp = pdA; pdA = pdB; pdB = tmp; }  // tracker follows buffer parity

    // ---- (6) rotate pipeline registers ----
    EnE0 = En2E0; EnE1 = En2E1; EnEm = En2Em;
    En2E0 = EwE0; En2E1 = EwE1; En2Em = EwEm;
    GnG0 = GwG0; GnG1 = GwG1;
    n1 = n2; n2 = d3.y;

    if (ci + 1 < nCh) __syncthreads();  // block-uniform condition
    cb ^= 1;
  }

  // epilogue: each (node, col) owned by exactly one lane -> plain stores
#pragma unroll
  for (int mt = 0; mt < MT_P; mt++) {
#pragma unroll
    for (int reg = 0; reg < 4; reg++) {
      int ld = mt * 16 + quad * 4 + reg;
      int node = nodeBase + ld;
      if (ld < DSTBLK && node < nNodes) {
#pragma unroll
        for (int nt = 0; nt < NT; nt++) {
          int col = colBase + nt * 16 + l16;
          float v = pacc[mt][nt][reg] + bias[col];
          if constexpr (BF16_RELU_OUT)
            ((unsigned short*)Hout)[(size_t)node * OUT + col] = f2bf(fmaxf(v, 0.f));
          else
            ((float*)Hout)[(size_t)node * OUT + col] = v;
        }
      }
    }
  }
}

extern "C" void kernel_launch(void* const* d_in, const int* in_sizes, int n_in,
                              void* d_out, int out_size, void* d_ws, size_t ws_size,
                              hipStream_t stream) {
  const int*   src   = (const int*)d_in[1];
  const int*   dst   = (const int*)d_in[2];
  const int*   etype = (const int*)d_in[3];
  const float* norm  = (const float*)d_in[4];
  const float* emb   = (const float*)d_in[5];
  const float* V1    = (const float*)d_in[6];
  const float* comp1 = (const float*)d_in[7];
  const float* bias1 = (const float*)d_in[8];
  const float* V2    = (const float*)d_in[9];
  const float* comp2 = (const float*)d_in[10];
  const float* bias2 = (const float*)d_in[11];
  float* out = (float*)d_out;

  const int N = in_sizes[0];  // 50000
  const int E = in_sizes[1];  // 1000000
  const int H = 128, O = 64;
  const int NB = (N + DSTBLK - 1) / DSTBLK;  // 758
  const int NBINS = NB * RELS;               // 12128
  const int EPAD_MAX = E + NBINS * 16;

  char* ws = (char*)d_ws;
  size_t off = 0;
  auto alloc = [&](size_t bytes) -> void* {
    void* p = ws + off;
    off += (bytes + 255) & ~(size_t)255;
    return p;
  };
  unsigned short* W1t  = (unsigned short*)alloc(sizeof(short) * RELS * H * H);
  unsigned short* W2t  = (unsigned short*)alloc(sizeof(short) * RELS * O * H);
  unsigned short* embh = (unsigned short*)alloc(sizeof(short) * (size_t)N * H);
  unsigned short* h1b  = (unsigned short*)alloc(sizeof(short) * (size_t)N * H);
  uint2* ebuf = (uint2*)alloc(sizeof(uint2) * EPAD_MAX);
  int* counts  = (int*)alloc(sizeof(int) * NBINS);
  int* cursor  = (int*)alloc(sizeof(int) * NBINS);
  int* offsets = (int*)alloc(sizeof(int) * (NBINS + 1));

  hipMemsetAsync(counts, 0, sizeof(int) * NBINS, stream);
  hipMemsetAsync(cursor, 0, sizeof(int) * NBINS, stream);

  cvt_bf16<<<((size_t)N * H / 8 + 255) / 256, 256, 0, stream>>>(emb, embh, N * H / 8);
  compute_w<<<(RELS * H * H + 255) / 256, 256, 0, stream>>>(comp1, V1, W1t, H);
  compute_w<<<(RELS * O * H + 255) / 256, 256, 0, stream>>>(comp2, V2, W2t, O);
  hist_bins<<<256, 256, 0, stream>>>(dst, etype, E, NBINS, counts);
  scan_offsets<<<1, 256, 0, stream>>>(counts, offsets, NBINS);
  scatter_bins<<<1024, 256, 0, stream>>>(src, dst, etype, norm, E, offsets, cursor, ebuf);

  rgcn_layer<128, true><<<NB, 256, 0, stream>>>(embh, W1t, ebuf, offsets, counts, bias1, (void*)h1b, N);
  rgcn_layer<64, false><<<NB, 256, 0, stream>>>(h1b, W2t, ebuf, offsets, counts, bias2, (void*)out, N);
}